// Round 8
// baseline (505.820 us; speedup 1.0000x reference)
//
#include <hip/hip_runtime.h>
#include <hip/hip_bf16.h>

// ---------------------------------------------------------------------------
// CriticWithGNN. Only edges with receiver < n_agents (~2%) matter (output is
// q[:n_agents]). Dense layers on MFMA with split-precision bf16:
// A*W ~= Alo*Whi + Ahi*Wlo + Ahi*Whi  (rel err ~2^-17, fp32-grade).
// R8: static register double-buffer for weight frags (hides L2 latency that
// left node_update at 43us / 1.5% MfmaUtil); counter-free chunked edge
// compaction -> 3 dispatches total (was 5; ~15-20us/boundary overhead).
// ---------------------------------------------------------------------------

#define STRIDE 260      // fp32 LDS row stride in words
#define FILT_CHUNK 4096 // edges scanned per filter block
#define CSTRIDE 1024    // compacted-edge slots per chunk (~84 expected, 11+ sigma)
#define TPC (CSTRIDE / 32)

typedef __attribute__((ext_vector_type(8))) short short8;
typedef __attribute__((ext_vector_type(4))) float floatx4;
union Frag8 { short8 s; uint u[4]; };

// hi = truncate-to-bf16 (mask), lo = RNE-bf16(f - hi)  [R5-proven, no spill]
__device__ __forceinline__ void cvt_hi_lo(const float4 f0, const float4 f1,
                                          Frag8& hi, Frag8& lo) {
    uint U[8] = { __float_as_uint(f0.x), __float_as_uint(f0.y),
                  __float_as_uint(f0.z), __float_as_uint(f0.w),
                  __float_as_uint(f1.x), __float_as_uint(f1.y),
                  __float_as_uint(f1.z), __float_as_uint(f1.w) };
    float F[8] = { f0.x, f0.y, f0.z, f0.w, f1.x, f1.y, f1.z, f1.w };
#pragma unroll
    for (int p = 0; p < 4; ++p) {
        uint a = U[2*p], b = U[2*p+1];
        hi.u[p] = (a >> 16) | (b & 0xFFFF0000u);
        float l0 = F[2*p]   - __uint_as_float(a & 0xFFFF0000u);
        float l1 = F[2*p+1] - __uint_as_float(b & 0xFFFF0000u);
        __hip_bfloat162 pl = __float22bfloat162_rn(make_float2(l0, l1));
        union { __hip_bfloat162 h; uint v; } cvt; cvt.h = pl;
        lo.u[p] = cvt.v;
    }
}

// ---- bf16 RNE split (weight packing) ----
__device__ __forceinline__ uint f2bf(float f) {
    uint u = __float_as_uint(f);
    return (u + 0x7FFFu + ((u >> 16) & 1u)) >> 16;
}
__device__ __forceinline__ float bf2f(uint h) { return __uint_as_float(h << 16); }
__device__ __forceinline__ uint split2(float f0, float f1, uint& lo) {
    uint h0 = f2bf(f0), h1 = f2bf(f1);
    uint l0 = f2bf(f0 - bf2f(h0)), l1 = f2bf(f1 - bf2f(h1));
    lo = l0 | (l1 << 16);
    return h0 | (h1 << 16);
}

// ---- packed-weight table (Wm1,Wm2,Wm3,Wa1,Wa2,Wa3,Wu1,Wu2,Wu3,Wh1,Wh2) ----
constexpr int PK_NIN[11]  = {128,256,256, 128,128,128, 192,256,256, 256,256};
constexpr int PK_NOUT[11] = {256,256,128, 128,128,128, 256,256,128, 256,256};
constexpr int pk_entries(int m) { return (PK_NIN[m]/32)*(PK_NOUT[m]/16)*64; }
constexpr int pk_cum(int m) { int s = 0; for (int i = 0; i < m; ++i) s += pk_entries(i); return s; }
constexpr int PK_TOTAL = pk_cum(11);       // 57344
constexpr int pk_off_hi(int m) { return 2*pk_cum(m); }
constexpr int pk_off_lo(int m) { return 2*pk_cum(m) + pk_entries(m); }

struct PackPtrs { const float* W[11]; };

// Merged dispatch: blocks [0,FB) compact chunk b's edges (receiver<n_agents)
// into edges[b*CSTRIDE ..], cnts[b]=count (no global counter!). Blocks
// [FB,FB+PB) pack weights into B-frag hi/lo planes AND zero aggr.
__global__ void pack_and_filter(PackPtrs P, uint4* __restrict__ pack,
                                const int* __restrict__ senders,
                                const int* __restrict__ receivers,
                                int E, int n_agents,
                                int* __restrict__ cnts,
                                int2* __restrict__ edges,
                                float* __restrict__ aggr, int aggrN, int FB) {
    __shared__ int lcount;
    __shared__ int2 lbuf[FILT_CHUNK];
    const int t = (int)threadIdx.x;
    if ((int)blockIdx.x < FB) {
        if (t == 0) lcount = 0;
        __syncthreads();
        int start = blockIdx.x * FILT_CHUNK;
        int end = min(start + FILT_CHUNK, E);
        for (int b0 = start; b0 < end; b0 += 256) {
            int idx = b0 + t;
            int r = -1, s = 0;
            bool pred = false;
            if (idx < end) {
                r = receivers[idx];
                pred = (r < n_agents);
                if (pred) s = senders[idx];
            }
            unsigned long long m = __ballot(pred);
            int lane = t & 63;
            int below = __popcll(m & ((1ull << lane) - 1));
            int cnt = __popcll(m);
            int wbase = 0;
            if (lane == 0 && cnt) wbase = atomicAdd(&lcount, cnt);
            wbase = __shfl(wbase, 0, 64);
            if (pred) lbuf[wbase + below] = make_int2(s, r);
        }
        __syncthreads();
        int c = min(lcount, CSTRIDE);
        if (t == 0) cnts[blockIdx.x] = c;
        int2* dst = edges + (size_t)blockIdx.x * CSTRIDE;
        for (int i = t; i < c; i += 256) dst[i] = lbuf[i];
        return;
    }
    int g = ((int)blockIdx.x - FB) * 256 + t;
    for (int i = g; i < aggrN; i += 224 * 256) aggr[i] = 0.f;   // PB=224
    if (g >= PK_TOTAL) return;
    int m = 0;
#pragma unroll
    for (int i = 1; i < 11; ++i) if (g >= pk_cum(i)) m = i;
    int local = g - pk_cum(m);
    const float* W = P.W[m];
    int NOUT = PK_NOUT[m], NT = NOUT / 16;
    int lane = local & 63;
    int tmp  = local >> 6;
    int nt = tmp % NT, kb = tmp / NT;
    int n  = nt * 16 + (lane & 15);
    int k0 = kb * 32 + (lane >> 4) * 8;
    uint hi[4], lo[4];
#pragma unroll
    for (int p = 0; p < 4; ++p) {
        float f0 = W[(size_t)(k0 + 2*p)     * NOUT + n];
        float f1 = W[(size_t)(k0 + 2*p + 1) * NOUT + n];
        hi[p] = split2(f0, f1, lo[p]);
    }
    pack[pk_off_hi(m) + local] = make_uint4(hi[0], hi[1], hi[2], hi[3]);
    pack[pk_off_lo(m) + local] = make_uint4(lo[0], lo[1], lo[2], lo[3]);
}

// ---- weight-frag load + MFMA compute helpers (static arrays only) --------
template<int NT, int NTW>
__device__ __forceinline__ void loadW(const uint4* __restrict__ Whi,
                                      const uint4* __restrict__ Wlo,
                                      int k, int lane, int wave,
                                      Frag8 (&bh)[NTW], Frag8 (&bl)[NTW]) {
#pragma unroll
    for (int i = 0; i < NTW; ++i) {
        int widx = (k * NT + wave * NTW + i) * 64 + lane;
        *(uint4*)bh[i].u = Whi[widx];
        *(uint4*)bl[i].u = Wlo[widx];
    }
}

template<int NTW>
__device__ __forceinline__ void compute2(const float* in_lds, int kb,
                                         int l15, int quad,
                                         Frag8 (&bh)[NTW], Frag8 (&bl)[NTW],
                                         floatx4 (&acc)[2][NTW]) {
    Frag8 ahi[2], alo[2];
#pragma unroll
    for (int mt = 0; mt < 2; ++mt) {
        const float* src = in_lds + (mt * 16 + l15) * STRIDE + kb * 32 + quad * 8;
        cvt_hi_lo(*(const float4*)src, *(const float4*)(src + 4), ahi[mt], alo[mt]);
    }
#pragma unroll
    for (int i = 0; i < NTW; ++i)
#pragma unroll
        for (int mt = 0; mt < 2; ++mt) {
            acc[mt][i] = __builtin_amdgcn_mfma_f32_16x16x32_bf16(alo[mt].s, bh[i].s, acc[mt][i], 0, 0, 0);
            acc[mt][i] = __builtin_amdgcn_mfma_f32_16x16x32_bf16(ahi[mt].s, bl[i].s, acc[mt][i], 0, 0, 0);
            acc[mt][i] = __builtin_amdgcn_mfma_f32_16x16x32_bf16(ahi[mt].s, bh[i].s, acc[mt][i], 0, 0, 0);
        }
}

template<int NTW>
__device__ __forceinline__ void compute1(const float* in_lds, int kb,
                                         int l15, int quad,
                                         Frag8 (&bh)[NTW], Frag8 (&bl)[NTW],
                                         floatx4 (&acc)[NTW]) {
    Frag8 ahi, alo;
    const float* src = in_lds + l15 * STRIDE + kb * 32 + quad * 8;
    cvt_hi_lo(*(const float4*)src, *(const float4*)(src + 4), ahi, alo);
#pragma unroll
    for (int i = 0; i < NTW; ++i) {
        acc[i] = __builtin_amdgcn_mfma_f32_16x16x32_bf16(alo.s, bh[i].s, acc[i], 0, 0, 0);
        acc[i] = __builtin_amdgcn_mfma_f32_16x16x32_bf16(ahi.s, bl[i].s, acc[i], 0, 0, 0);
        acc[i] = __builtin_amdgcn_mfma_f32_16x16x32_bf16(ahi.s, bh[i].s, acc[i], 0, 0, 0);
    }
}

// ---- MFMA dense layer, 32-row tile, weight register double-buffer --------
template<int NIN, int NOUT, bool RELU>
__device__ __forceinline__ void mfma_layer(const float* in_lds, float* out_lds,
                                           const uint4* __restrict__ Whi,
                                           const uint4* __restrict__ Wlo,
                                           const float* __restrict__ b) {
    constexpr int KB = NIN / 32, NT = NOUT / 16, NTW = NT / 4;
    static_assert(KB % 2 == 0, "even KB for pairwise double-buffer");
    const int t = (int)threadIdx.x;
    const int wave = t >> 6, lane = t & 63, l15 = t & 15, quad = (t >> 4) & 3;

    floatx4 acc[2][NTW];
#pragma unroll
    for (int mt = 0; mt < 2; ++mt)
#pragma unroll
        for (int i = 0; i < NTW; ++i) acc[mt][i] = (floatx4){0.f, 0.f, 0.f, 0.f};

    Frag8 WAh[NTW], WAl[NTW], WBh[NTW], WBl[NTW];
    loadW<NT, NTW>(Whi, Wlo, 0, lane, wave, WAh, WAl);
#pragma unroll
    for (int kb = 0; kb < KB; kb += 2) {
        loadW<NT, NTW>(Whi, Wlo, kb + 1, lane, wave, WBh, WBl);
        compute2<NTW>(in_lds, kb, l15, quad, WAh, WAl, acc);
        if (kb + 2 < KB) loadW<NT, NTW>(Whi, Wlo, kb + 2, lane, wave, WAh, WAl);
        compute2<NTW>(in_lds, kb + 1, l15, quad, WBh, WBl, acc);
    }
#pragma unroll
    for (int i = 0; i < NTW; ++i) {
        int n = (wave * NTW + i) * 16 + l15;
        float bias = b[n];
#pragma unroll
        for (int mt = 0; mt < 2; ++mt)
#pragma unroll
            for (int r = 0; r < 4; ++r) {
                float v = acc[mt][i][r] + bias;
                if (RELU) v = fmaxf(v, 0.f);
                out_lds[(mt * 16 + quad * 4 + r) * STRIDE + n] = v;
            }
    }
}

// 16-row variant with output column offset (node pipeline).
template<int NIN, int NOUT, bool RELU, int OOFF>
__device__ __forceinline__ void mfma_layer16(const float* in_lds, float* out_lds,
                                             const uint4* __restrict__ Whi,
                                             const uint4* __restrict__ Wlo,
                                             const float* __restrict__ b) {
    constexpr int KB = NIN / 32, NT = NOUT / 16, NTW = NT / 4;
    static_assert(KB % 2 == 0, "even KB");
    const int t = (int)threadIdx.x;
    const int wave = t >> 6, lane = t & 63, l15 = t & 15, quad = (t >> 4) & 3;

    floatx4 acc[NTW];
#pragma unroll
    for (int i = 0; i < NTW; ++i) acc[i] = (floatx4){0.f, 0.f, 0.f, 0.f};

    Frag8 WAh[NTW], WAl[NTW], WBh[NTW], WBl[NTW];
    loadW<NT, NTW>(Whi, Wlo, 0, lane, wave, WAh, WAl);
#pragma unroll
    for (int kb = 0; kb < KB; kb += 2) {
        loadW<NT, NTW>(Whi, Wlo, kb + 1, lane, wave, WBh, WBl);
        compute1<NTW>(in_lds, kb, l15, quad, WAh, WAl, acc);
        if (kb + 2 < KB) loadW<NT, NTW>(Whi, Wlo, kb + 2, lane, wave, WAh, WAl);
        compute1<NTW>(in_lds, kb + 1, l15, quad, WBh, WBl, acc);
    }
#pragma unroll
    for (int i = 0; i < NTW; ++i) {
        int n = (wave * NTW + i) * 16 + l15;
        float bias = b[n];
#pragma unroll
        for (int r = 0; r < 4; ++r) {
            float v = acc[i][r] + bias;
            if (RELU) v = fmaxf(v, 0.f);
            out_lds[(quad * 4 + r) * STRIDE + OOFF + n] = v;
        }
    }
}

// ---- edge message MLP over chunked compacted edges + atomic scatter ------
#define ETE 32
__global__ __launch_bounds__(256, 2)
void edge_mlp(const float* __restrict__ x, const int2* __restrict__ edges,
              const int* __restrict__ cnts, float* __restrict__ aggr,
              const uint4* __restrict__ pack,
              const float* __restrict__ bm1, const float* __restrict__ bm2,
              const float* __restrict__ bm3, int FB) {
    __shared__ float bufA[ETE * STRIDE];
    __shared__ float bufB[ETE * STRIDE];
    __shared__ int sL[ETE], rL[ETE];
    const int t = (int)threadIdx.x;
    const int vtiles = FB * TPC;
    for (int vt = (int)blockIdx.x; vt < vtiles; vt += (int)gridDim.x) {
        const int chunk = vt / TPC, ti = vt % TPC;
        const int cnt = cnts[chunk];
        if (ti * 32 >= cnt) continue;
        const int2* ce = edges + (size_t)chunk * CSTRIDE;
        const int base = ti * 32;
        if (t < ETE) {
            int eg = base + t;
            int2 ed = (eg < cnt) ? ce[eg] : make_int2(0, -1);
            sL[t] = ed.x; rL[t] = ed.y;
        }
        __syncthreads();
        for (int idx = t; idx < ETE * 32; idx += 256) {
            int e = idx >> 5;
            int f4 = (idx & 31) * 4;
            int node = (f4 < 64) ? sL[e] : rL[e];
            float4 v = make_float4(0.f, 0.f, 0.f, 0.f);
            if (rL[e] >= 0) v = *(const float4*)(x + (size_t)node * 64 + (f4 & 63));
            *(float4*)(bufA + e * STRIDE + f4) = v;
        }
        __syncthreads();
        mfma_layer<128, 256, true >(bufA, bufB, pack + pk_off_hi(0), pack + pk_off_lo(0), bm1);
        __syncthreads();
        mfma_layer<256, 256, true >(bufB, bufA, pack + pk_off_hi(1), pack + pk_off_lo(1), bm2);
        __syncthreads();
        mfma_layer<256, 128, false>(bufA, bufB, pack + pk_off_hi(2), pack + pk_off_lo(2), bm3);
        __syncthreads();
        for (int idx = t; idx < ETE * 128; idx += 256) {
            int e = idx >> 7, o = idx & 127;
            if (rL[e] >= 0) {
                atomicAdd(&aggr[(size_t)rL[e] * 128 + o], bufB[e * STRIDE + o]);
            }
        }
        __syncthreads();
    }
}

// ---- fused node pipeline, MFMA: 16 nodes/block, 64 blocks ----------------
__global__ __launch_bounds__(256, 1)
void node_update(const float* __restrict__ x, const float* __restrict__ actions,
                 const float* __restrict__ aggr, int n_agents,
                 const uint4* __restrict__ pack,
                 const float* __restrict__ ba1, const float* __restrict__ ba2,
                 const float* __restrict__ ba3,
                 const float* __restrict__ bu1, const float* __restrict__ bu2,
                 const float* __restrict__ bu3,
                 const float* __restrict__ Wact, const float* __restrict__ bact,
                 const float* __restrict__ bh1, const float* __restrict__ bh2,
                 const float* __restrict__ Wq,  const float* __restrict__ bq,
                 float* __restrict__ out) {
    __shared__ float bufA[16 * STRIDE];
    __shared__ float bufB[16 * STRIDE];
    __shared__ float qpart[16][17];
    const int t = (int)threadIdx.x;
    const int base = (int)blockIdx.x * 16;

    for (int idx = t; idx < 16 * 32; idx += 256) {
        int e = idx >> 5, f4 = (idx & 31) * 4;
        float4 v = make_float4(0.f, 0.f, 0.f, 0.f);
        if (base + e < n_agents) v = *(const float4*)(aggr + (size_t)(base + e) * 128 + f4);
        *(float4*)(bufA + e * STRIDE + f4) = v;
    }
    __syncthreads();
    mfma_layer16<128, 128, true,  0 >(bufA, bufB, pack + pk_off_hi(3), pack + pk_off_lo(3), ba1);
    __syncthreads();
    mfma_layer16<128, 128, true,  0 >(bufB, bufA, pack + pk_off_hi(4), pack + pk_off_lo(4), ba2);
    __syncthreads();
    mfma_layer16<128, 128, false, 64>(bufA, bufB, pack + pk_off_hi(5), pack + pk_off_lo(5), ba3);
    for (int idx = t; idx < 16 * 16; idx += 256) {
        int e = idx >> 4, f4 = (idx & 15) * 4;
        float4 v = make_float4(0.f, 0.f, 0.f, 0.f);
        if (base + e < n_agents) v = *(const float4*)(x + (size_t)(base + e) * 64 + f4);
        *(float4*)(bufB + e * STRIDE + f4) = v;
    }
    __syncthreads();
    mfma_layer16<192, 256, true,  0 >(bufB, bufA, pack + pk_off_hi(6), pack + pk_off_lo(6), bu1);
    __syncthreads();
    mfma_layer16<256, 256, true,  0 >(bufA, bufB, pack + pk_off_hi(7), pack + pk_off_lo(7), bu2);
    __syncthreads();
    mfma_layer16<256, 128, false, 0 >(bufB, bufA, pack + pk_off_hi(8), pack + pk_off_lo(8), bu3);
    {
        int e = t >> 4, c0 = (t & 15) * 8;
        float accp[8];
#pragma unroll
        for (int c = 0; c < 8; ++c) accp[c] = bact[c0 + c];
        if (base + e < n_agents) {
#pragma unroll
            for (int k = 0; k < 16; ++k) {
                float av = actions[(size_t)(base + e) * 16 + k];
#pragma unroll
                for (int c = 0; c < 8; ++c)
                    accp[c] += av * Wact[(size_t)k * 128 + c0 + c];
            }
        }
#pragma unroll
        for (int c = 0; c < 8; ++c)
            bufA[e * STRIDE + 128 + c0 + c] = fmaxf(accp[c], 0.f);
    }
    __syncthreads();
    mfma_layer16<256, 256, true, 0>(bufA, bufB, pack + pk_off_hi(9),  pack + pk_off_lo(9),  bh1);
    __syncthreads();
    mfma_layer16<256, 256, true, 0>(bufB, bufA, pack + pk_off_hi(10), pack + pk_off_lo(10), bh2);
    __syncthreads();
    {
        int e = t >> 4, g = t & 15;
        const float* z = bufA + e * STRIDE + g * 16;
        const float* w = Wq + g * 16;
        float p = 0.f;
#pragma unroll
        for (int j = 0; j < 16; j += 4) {
            float4 zv = *(const float4*)(z + j);
            float4 wv = *(const float4*)(w + j);
            p += zv.x * wv.x + zv.y * wv.y + zv.z * wv.z + zv.w * wv.w;
        }
        qpart[e][g] = p;
    }
    __syncthreads();
    if (t < 16 && base + t < n_agents) {
        float s = bq[0];
#pragma unroll
        for (int g = 0; g < 16; ++g) s += qpart[t][g];
        out[base + t] = s;
    }
}

extern "C" void kernel_launch(void* const* d_in, const int* in_sizes, int n_in,
                              void* d_out, int out_size, void* d_ws, size_t ws_size,
                              hipStream_t stream) {
    const float* x        = (const float*)d_in[0];
    const float* actions  = (const float*)d_in[1];
    const int*   senders  = (const int*)d_in[2];
    const int*   receivers= (const int*)d_in[3];
    const float* Wm1 = (const float*)d_in[5],  *bm1 = (const float*)d_in[6];
    const float* Wm2 = (const float*)d_in[7],  *bm2 = (const float*)d_in[8];
    const float* Wm3 = (const float*)d_in[9],  *bm3 = (const float*)d_in[10];
    const float* Wa1 = (const float*)d_in[11], *ba1 = (const float*)d_in[12];
    const float* Wa2 = (const float*)d_in[13], *ba2 = (const float*)d_in[14];
    const float* Wa3 = (const float*)d_in[15], *ba3 = (const float*)d_in[16];
    const float* Wu1 = (const float*)d_in[17], *bu1 = (const float*)d_in[18];
    const float* Wu2 = (const float*)d_in[19], *bu2 = (const float*)d_in[20];
    const float* Wu3 = (const float*)d_in[21], *bu3 = (const float*)d_in[22];
    const float* Wact= (const float*)d_in[23], *bact= (const float*)d_in[24];
    const float* Wh1 = (const float*)d_in[25], *bh1 = (const float*)d_in[26];
    const float* Wh2 = (const float*)d_in[27], *bh2 = (const float*)d_in[28];
    const float* Wq  = (const float*)d_in[29], *bq  = (const float*)d_in[30];

    const int E = in_sizes[2];
    const int n_agents = out_size;

    // ws: [0,1024) cnts(FB ints) | [1024,+512K) aggr | pack (1.84M) | edges
    char* ws = (char*)d_ws;
    int*   cnts = (int*)ws;
    float* aggr = (float*)(ws + 1024);
    const size_t packOff = 1024 + (size_t)n_agents * 128 * sizeof(float);
    uint4* pack = (uint4*)(ws + packOff);
    const size_t packBytes = (size_t)2 * PK_TOTAL * 16;
    const size_t edgeOff = packOff + packBytes;
    int2* edges = (int2*)(ws + edgeOff);

    const int FB = (E + FILT_CHUNK - 1) / FILT_CHUNK;   // 196
    const int PB = (PK_TOTAL + 255) / 256;              // 224

    PackPtrs P;
    P.W[0] = Wm1; P.W[1] = Wm2; P.W[2] = Wm3;
    P.W[3] = Wa1; P.W[4] = Wa2; P.W[5] = Wa3;
    P.W[6] = Wu1; P.W[7] = Wu2; P.W[8] = Wu3;
    P.W[9] = Wh1; P.W[10] = Wh2;
    pack_and_filter<<<FB + PB, 256, 0, stream>>>(P, pack, senders, receivers,
                                                 E, n_agents, cnts, edges,
                                                 aggr, n_agents * 128, FB);

    edge_mlp<<<512, 256, 0, stream>>>(x, edges, cnts, aggr, pack,
                                      bm1, bm2, bm3, FB);

    node_update<<<(n_agents + 15) / 16, 256, 0, stream>>>(
        x, actions, aggr, n_agents, pack,
        ba1, ba2, ba3, bu1, bu2, bu3, Wact, bact, bh1, bh2, Wq, bq,
        (float*)d_out);
}

// Round 9
// 244.728 us; speedup vs baseline: 2.0669x; 2.0669x over previous
//
#include <hip/hip_runtime.h>
#include <hip/hip_bf16.h>

// ---------------------------------------------------------------------------
// CriticWithGNN. Only edges with receiver < n_agents (~2%) matter (output is
// q[:n_agents]). Dense layers on MFMA with split-precision bf16:
// A*W ~= Alo*Whi + Ahi*Wlo + Ahi*Whi  (rel err ~2^-17, fp32-grade).
// R9: fix R8's vtile->block stride aliasing (TPC=32 divided grid=512, so all
// real tiles hit 48 blocks -> 2.6% occupancy). ti-MAJOR mapping spreads the
// ~590 real tiles over all 512 blocks. Everything else = R8.
// ---------------------------------------------------------------------------

#define STRIDE 260      // fp32 LDS row stride in words
#define FILT_CHUNK 4096 // edges scanned per filter block
#define CSTRIDE 1024    // compacted-edge slots per chunk (~84 expected)
#define TPC (CSTRIDE / 32)

typedef __attribute__((ext_vector_type(8))) short short8;
typedef __attribute__((ext_vector_type(4))) float floatx4;
union Frag8 { short8 s; uint u[4]; };

// hi = truncate-to-bf16 (mask), lo = RNE-bf16(f - hi)  [R5-proven, no spill]
__device__ __forceinline__ void cvt_hi_lo(const float4 f0, const float4 f1,
                                          Frag8& hi, Frag8& lo) {
    uint U[8] = { __float_as_uint(f0.x), __float_as_uint(f0.y),
                  __float_as_uint(f0.z), __float_as_uint(f0.w),
                  __float_as_uint(f1.x), __float_as_uint(f1.y),
                  __float_as_uint(f1.z), __float_as_uint(f1.w) };
    float F[8] = { f0.x, f0.y, f0.z, f0.w, f1.x, f1.y, f1.z, f1.w };
#pragma unroll
    for (int p = 0; p < 4; ++p) {
        uint a = U[2*p], b = U[2*p+1];
        hi.u[p] = (a >> 16) | (b & 0xFFFF0000u);
        float l0 = F[2*p]   - __uint_as_float(a & 0xFFFF0000u);
        float l1 = F[2*p+1] - __uint_as_float(b & 0xFFFF0000u);
        __hip_bfloat162 pl = __float22bfloat162_rn(make_float2(l0, l1));
        union { __hip_bfloat162 h; uint v; } cvt; cvt.h = pl;
        lo.u[p] = cvt.v;
    }
}

// ---- bf16 RNE split (weight packing) ----
__device__ __forceinline__ uint f2bf(float f) {
    uint u = __float_as_uint(f);
    return (u + 0x7FFFu + ((u >> 16) & 1u)) >> 16;
}
__device__ __forceinline__ float bf2f(uint h) { return __uint_as_float(h << 16); }
__device__ __forceinline__ uint split2(float f0, float f1, uint& lo) {
    uint h0 = f2bf(f0), h1 = f2bf(f1);
    uint l0 = f2bf(f0 - bf2f(h0)), l1 = f2bf(f1 - bf2f(h1));
    lo = l0 | (l1 << 16);
    return h0 | (h1 << 16);
}

// ---- packed-weight table (Wm1,Wm2,Wm3,Wa1,Wa2,Wa3,Wu1,Wu2,Wu3,Wh1,Wh2) ----
constexpr int PK_NIN[11]  = {128,256,256, 128,128,128, 192,256,256, 256,256};
constexpr int PK_NOUT[11] = {256,256,128, 128,128,128, 256,256,128, 256,256};
constexpr int pk_entries(int m) { return (PK_NIN[m]/32)*(PK_NOUT[m]/16)*64; }
constexpr int pk_cum(int m) { int s = 0; for (int i = 0; i < m; ++i) s += pk_entries(i); return s; }
constexpr int PK_TOTAL = pk_cum(11);       // 57344
constexpr int pk_off_hi(int m) { return 2*pk_cum(m); }
constexpr int pk_off_lo(int m) { return 2*pk_cum(m) + pk_entries(m); }

struct PackPtrs { const float* W[11]; };

// Merged dispatch: blocks [0,FB) compact chunk b's edges (receiver<n_agents)
// into edges[b*CSTRIDE ..], cnts[b]=count. Blocks [FB,FB+PB) pack weights
// into B-frag hi/lo planes AND zero aggr.
__global__ void pack_and_filter(PackPtrs P, uint4* __restrict__ pack,
                                const int* __restrict__ senders,
                                const int* __restrict__ receivers,
                                int E, int n_agents,
                                int* __restrict__ cnts,
                                int2* __restrict__ edges,
                                float* __restrict__ aggr, int aggrN, int FB) {
    __shared__ int lcount;
    __shared__ int2 lbuf[FILT_CHUNK];
    const int t = (int)threadIdx.x;
    if ((int)blockIdx.x < FB) {
        if (t == 0) lcount = 0;
        __syncthreads();
        int start = blockIdx.x * FILT_CHUNK;
        int end = min(start + FILT_CHUNK, E);
        for (int b0 = start; b0 < end; b0 += 256) {
            int idx = b0 + t;
            int r = -1, s = 0;
            bool pred = false;
            if (idx < end) {
                r = receivers[idx];
                pred = (r < n_agents);
                if (pred) s = senders[idx];
            }
            unsigned long long m = __ballot(pred);
            int lane = t & 63;
            int below = __popcll(m & ((1ull << lane) - 1));
            int cnt = __popcll(m);
            int wbase = 0;
            if (lane == 0 && cnt) wbase = atomicAdd(&lcount, cnt);
            wbase = __shfl(wbase, 0, 64);
            if (pred) lbuf[wbase + below] = make_int2(s, r);
        }
        __syncthreads();
        int c = min(lcount, CSTRIDE);
        if (t == 0) cnts[blockIdx.x] = c;
        int2* dst = edges + (size_t)blockIdx.x * CSTRIDE;
        for (int i = t; i < c; i += 256) dst[i] = lbuf[i];
        return;
    }
    int g = ((int)blockIdx.x - FB) * 256 + t;
    for (int i = g; i < aggrN; i += 224 * 256) aggr[i] = 0.f;   // PB=224
    if (g >= PK_TOTAL) return;
    int m = 0;
#pragma unroll
    for (int i = 1; i < 11; ++i) if (g >= pk_cum(i)) m = i;
    int local = g - pk_cum(m);
    const float* W = P.W[m];
    int NOUT = PK_NOUT[m], NT = NOUT / 16;
    int lane = local & 63;
    int tmp  = local >> 6;
    int nt = tmp % NT, kb = tmp / NT;
    int n  = nt * 16 + (lane & 15);
    int k0 = kb * 32 + (lane >> 4) * 8;
    uint hi[4], lo[4];
#pragma unroll
    for (int p = 0; p < 4; ++p) {
        float f0 = W[(size_t)(k0 + 2*p)     * NOUT + n];
        float f1 = W[(size_t)(k0 + 2*p + 1) * NOUT + n];
        hi[p] = split2(f0, f1, lo[p]);
    }
    pack[pk_off_hi(m) + local] = make_uint4(hi[0], hi[1], hi[2], hi[3]);
    pack[pk_off_lo(m) + local] = make_uint4(lo[0], lo[1], lo[2], lo[3]);
}

// ---- weight-frag load + MFMA compute helpers (static arrays only) --------
template<int NT, int NTW>
__device__ __forceinline__ void loadW(const uint4* __restrict__ Whi,
                                      const uint4* __restrict__ Wlo,
                                      int k, int lane, int wave,
                                      Frag8 (&bh)[NTW], Frag8 (&bl)[NTW]) {
#pragma unroll
    for (int i = 0; i < NTW; ++i) {
        int widx = (k * NT + wave * NTW + i) * 64 + lane;
        *(uint4*)bh[i].u = Whi[widx];
        *(uint4*)bl[i].u = Wlo[widx];
    }
}

template<int NTW>
__device__ __forceinline__ void compute2(const float* in_lds, int kb,
                                         int l15, int quad,
                                         Frag8 (&bh)[NTW], Frag8 (&bl)[NTW],
                                         floatx4 (&acc)[2][NTW]) {
    Frag8 ahi[2], alo[2];
#pragma unroll
    for (int mt = 0; mt < 2; ++mt) {
        const float* src = in_lds + (mt * 16 + l15) * STRIDE + kb * 32 + quad * 8;
        cvt_hi_lo(*(const float4*)src, *(const float4*)(src + 4), ahi[mt], alo[mt]);
    }
#pragma unroll
    for (int i = 0; i < NTW; ++i)
#pragma unroll
        for (int mt = 0; mt < 2; ++mt) {
            acc[mt][i] = __builtin_amdgcn_mfma_f32_16x16x32_bf16(alo[mt].s, bh[i].s, acc[mt][i], 0, 0, 0);
            acc[mt][i] = __builtin_amdgcn_mfma_f32_16x16x32_bf16(ahi[mt].s, bl[i].s, acc[mt][i], 0, 0, 0);
            acc[mt][i] = __builtin_amdgcn_mfma_f32_16x16x32_bf16(ahi[mt].s, bh[i].s, acc[mt][i], 0, 0, 0);
        }
}

template<int NTW>
__device__ __forceinline__ void compute1(const float* in_lds, int kb,
                                         int l15, int quad,
                                         Frag8 (&bh)[NTW], Frag8 (&bl)[NTW],
                                         floatx4 (&acc)[NTW]) {
    Frag8 ahi, alo;
    const float* src = in_lds + l15 * STRIDE + kb * 32 + quad * 8;
    cvt_hi_lo(*(const float4*)src, *(const float4*)(src + 4), ahi, alo);
#pragma unroll
    for (int i = 0; i < NTW; ++i) {
        acc[i] = __builtin_amdgcn_mfma_f32_16x16x32_bf16(alo.s, bh[i].s, acc[i], 0, 0, 0);
        acc[i] = __builtin_amdgcn_mfma_f32_16x16x32_bf16(ahi.s, bl[i].s, acc[i], 0, 0, 0);
        acc[i] = __builtin_amdgcn_mfma_f32_16x16x32_bf16(ahi.s, bh[i].s, acc[i], 0, 0, 0);
    }
}

// ---- MFMA dense layer, 32-row tile, weight register double-buffer --------
template<int NIN, int NOUT, bool RELU>
__device__ __forceinline__ void mfma_layer(const float* in_lds, float* out_lds,
                                           const uint4* __restrict__ Whi,
                                           const uint4* __restrict__ Wlo,
                                           const float* __restrict__ b) {
    constexpr int KB = NIN / 32, NT = NOUT / 16, NTW = NT / 4;
    static_assert(KB % 2 == 0, "even KB for pairwise double-buffer");
    const int t = (int)threadIdx.x;
    const int wave = t >> 6, lane = t & 63, l15 = t & 15, quad = (t >> 4) & 3;

    floatx4 acc[2][NTW];
#pragma unroll
    for (int mt = 0; mt < 2; ++mt)
#pragma unroll
        for (int i = 0; i < NTW; ++i) acc[mt][i] = (floatx4){0.f, 0.f, 0.f, 0.f};

    Frag8 WAh[NTW], WAl[NTW], WBh[NTW], WBl[NTW];
    loadW<NT, NTW>(Whi, Wlo, 0, lane, wave, WAh, WAl);
#pragma unroll
    for (int kb = 0; kb < KB; kb += 2) {
        loadW<NT, NTW>(Whi, Wlo, kb + 1, lane, wave, WBh, WBl);
        compute2<NTW>(in_lds, kb, l15, quad, WAh, WAl, acc);
        if (kb + 2 < KB) loadW<NT, NTW>(Whi, Wlo, kb + 2, lane, wave, WAh, WAl);
        compute2<NTW>(in_lds, kb + 1, l15, quad, WBh, WBl, acc);
    }
#pragma unroll
    for (int i = 0; i < NTW; ++i) {
        int n = (wave * NTW + i) * 16 + l15;
        float bias = b[n];
#pragma unroll
        for (int mt = 0; mt < 2; ++mt)
#pragma unroll
            for (int r = 0; r < 4; ++r) {
                float v = acc[mt][i][r] + bias;
                if (RELU) v = fmaxf(v, 0.f);
                out_lds[(mt * 16 + quad * 4 + r) * STRIDE + n] = v;
            }
    }
}

// 16-row variant with output column offset (node pipeline).
template<int NIN, int NOUT, bool RELU, int OOFF>
__device__ __forceinline__ void mfma_layer16(const float* in_lds, float* out_lds,
                                             const uint4* __restrict__ Whi,
                                             const uint4* __restrict__ Wlo,
                                             const float* __restrict__ b) {
    constexpr int KB = NIN / 32, NT = NOUT / 16, NTW = NT / 4;
    static_assert(KB % 2 == 0, "even KB");
    const int t = (int)threadIdx.x;
    const int wave = t >> 6, lane = t & 63, l15 = t & 15, quad = (t >> 4) & 3;

    floatx4 acc[NTW];
#pragma unroll
    for (int i = 0; i < NTW; ++i) acc[i] = (floatx4){0.f, 0.f, 0.f, 0.f};

    Frag8 WAh[NTW], WAl[NTW], WBh[NTW], WBl[NTW];
    loadW<NT, NTW>(Whi, Wlo, 0, lane, wave, WAh, WAl);
#pragma unroll
    for (int kb = 0; kb < KB; kb += 2) {
        loadW<NT, NTW>(Whi, Wlo, kb + 1, lane, wave, WBh, WBl);
        compute1<NTW>(in_lds, kb, l15, quad, WAh, WAl, acc);
        if (kb + 2 < KB) loadW<NT, NTW>(Whi, Wlo, kb + 2, lane, wave, WAh, WAl);
        compute1<NTW>(in_lds, kb + 1, l15, quad, WBh, WBl, acc);
    }
#pragma unroll
    for (int i = 0; i < NTW; ++i) {
        int n = (wave * NTW + i) * 16 + l15;
        float bias = b[n];
#pragma unroll
        for (int r = 0; r < 4; ++r) {
            float v = acc[i][r] + bias;
            if (RELU) v = fmaxf(v, 0.f);
            out_lds[(quad * 4 + r) * STRIDE + OOFF + n] = v;
        }
    }
}

// ---- edge message MLP over chunked compacted edges + atomic scatter ------
// ti-MAJOR vtile mapping: chunk = vt % FB. Real tiles (ti < ~3) occupy the
// contiguous range vt < ~3*FB, spreading evenly over the 512-block grid
// (R8's chunk-major mapping aliased mod 512 onto 48 blocks -> 355us).
#define ETE 32
__global__ __launch_bounds__(256, 2)
void edge_mlp(const float* __restrict__ x, const int2* __restrict__ edges,
              const int* __restrict__ cnts, float* __restrict__ aggr,
              const uint4* __restrict__ pack,
              const float* __restrict__ bm1, const float* __restrict__ bm2,
              const float* __restrict__ bm3, int FB) {
    __shared__ float bufA[ETE * STRIDE];
    __shared__ float bufB[ETE * STRIDE];
    __shared__ int sL[ETE], rL[ETE];
    const int t = (int)threadIdx.x;
    const int vtiles = FB * TPC;
    for (int vt = (int)blockIdx.x; vt < vtiles; vt += (int)gridDim.x) {
        const int chunk = vt % FB, ti = vt / FB;
        const int cnt = cnts[chunk];
        if (ti * 32 >= cnt) continue;
        const int2* ce = edges + (size_t)chunk * CSTRIDE;
        const int base = ti * 32;
        if (t < ETE) {
            int eg = base + t;
            int2 ed = (eg < cnt) ? ce[eg] : make_int2(0, -1);
            sL[t] = ed.x; rL[t] = ed.y;
        }
        __syncthreads();
        for (int idx = t; idx < ETE * 32; idx += 256) {
            int e = idx >> 5;
            int f4 = (idx & 31) * 4;
            int node = (f4 < 64) ? sL[e] : rL[e];
            float4 v = make_float4(0.f, 0.f, 0.f, 0.f);
            if (rL[e] >= 0) v = *(const float4*)(x + (size_t)node * 64 + (f4 & 63));
            *(float4*)(bufA + e * STRIDE + f4) = v;
        }
        __syncthreads();
        mfma_layer<128, 256, true >(bufA, bufB, pack + pk_off_hi(0), pack + pk_off_lo(0), bm1);
        __syncthreads();
        mfma_layer<256, 256, true >(bufB, bufA, pack + pk_off_hi(1), pack + pk_off_lo(1), bm2);
        __syncthreads();
        mfma_layer<256, 128, false>(bufA, bufB, pack + pk_off_hi(2), pack + pk_off_lo(2), bm3);
        __syncthreads();
        for (int idx = t; idx < ETE * 128; idx += 256) {
            int e = idx >> 7, o = idx & 127;
            if (rL[e] >= 0) {
                atomicAdd(&aggr[(size_t)rL[e] * 128 + o], bufB[e * STRIDE + o]);
            }
        }
        __syncthreads();
    }
}

// ---- fused node pipeline, MFMA: 16 nodes/block, 64 blocks ----------------
__global__ __launch_bounds__(256, 1)
void node_update(const float* __restrict__ x, const float* __restrict__ actions,
                 const float* __restrict__ aggr, int n_agents,
                 const uint4* __restrict__ pack,
                 const float* __restrict__ ba1, const float* __restrict__ ba2,
                 const float* __restrict__ ba3,
                 const float* __restrict__ bu1, const float* __restrict__ bu2,
                 const float* __restrict__ bu3,
                 const float* __restrict__ Wact, const float* __restrict__ bact,
                 const float* __restrict__ bh1, const float* __restrict__ bh2,
                 const float* __restrict__ Wq,  const float* __restrict__ bq,
                 float* __restrict__ out) {
    __shared__ float bufA[16 * STRIDE];
    __shared__ float bufB[16 * STRIDE];
    __shared__ float qpart[16][17];
    const int t = (int)threadIdx.x;
    const int base = (int)blockIdx.x * 16;

    for (int idx = t; idx < 16 * 32; idx += 256) {
        int e = idx >> 5, f4 = (idx & 31) * 4;
        float4 v = make_float4(0.f, 0.f, 0.f, 0.f);
        if (base + e < n_agents) v = *(const float4*)(aggr + (size_t)(base + e) * 128 + f4);
        *(float4*)(bufA + e * STRIDE + f4) = v;
    }
    __syncthreads();
    mfma_layer16<128, 128, true,  0 >(bufA, bufB, pack + pk_off_hi(3), pack + pk_off_lo(3), ba1);
    __syncthreads();
    mfma_layer16<128, 128, true,  0 >(bufB, bufA, pack + pk_off_hi(4), pack + pk_off_lo(4), ba2);
    __syncthreads();
    mfma_layer16<128, 128, false, 64>(bufA, bufB, pack + pk_off_hi(5), pack + pk_off_lo(5), ba3);
    for (int idx = t; idx < 16 * 16; idx += 256) {
        int e = idx >> 4, f4 = (idx & 15) * 4;
        float4 v = make_float4(0.f, 0.f, 0.f, 0.f);
        if (base + e < n_agents) v = *(const float4*)(x + (size_t)(base + e) * 64 + f4);
        *(float4*)(bufB + e * STRIDE + f4) = v;
    }
    __syncthreads();
    mfma_layer16<192, 256, true,  0 >(bufB, bufA, pack + pk_off_hi(6), pack + pk_off_lo(6), bu1);
    __syncthreads();
    mfma_layer16<256, 256, true,  0 >(bufA, bufB, pack + pk_off_hi(7), pack + pk_off_lo(7), bu2);
    __syncthreads();
    mfma_layer16<256, 128, false, 0 >(bufB, bufA, pack + pk_off_hi(8), pack + pk_off_lo(8), bu3);
    {
        int e = t >> 4, c0 = (t & 15) * 8;
        float accp[8];
#pragma unroll
        for (int c = 0; c < 8; ++c) accp[c] = bact[c0 + c];
        if (base + e < n_agents) {
#pragma unroll
            for (int k = 0; k < 16; ++k) {
                float av = actions[(size_t)(base + e) * 16 + k];
#pragma unroll
                for (int c = 0; c < 8; ++c)
                    accp[c] += av * Wact[(size_t)k * 128 + c0 + c];
            }
        }
#pragma unroll
        for (int c = 0; c < 8; ++c)
            bufA[e * STRIDE + 128 + c0 + c] = fmaxf(accp[c], 0.f);
    }
    __syncthreads();
    mfma_layer16<256, 256, true, 0>(bufA, bufB, pack + pk_off_hi(9),  pack + pk_off_lo(9),  bh1);
    __syncthreads();
    mfma_layer16<256, 256, true, 0>(bufB, bufA, pack + pk_off_hi(10), pack + pk_off_lo(10), bh2);
    __syncthreads();
    {
        int e = t >> 4, g = t & 15;
        const float* z = bufA + e * STRIDE + g * 16;
        const float* w = Wq + g * 16;
        float p = 0.f;
#pragma unroll
        for (int j = 0; j < 16; j += 4) {
            float4 zv = *(const float4*)(z + j);
            float4 wv = *(const float4*)(w + j);
            p += zv.x * wv.x + zv.y * wv.y + zv.z * wv.z + zv.w * wv.w;
        }
        qpart[e][g] = p;
    }
    __syncthreads();
    if (t < 16 && base + t < n_agents) {
        float s = bq[0];
#pragma unroll
        for (int g = 0; g < 16; ++g) s += qpart[t][g];
        out[base + t] = s;
    }
}

extern "C" void kernel_launch(void* const* d_in, const int* in_sizes, int n_in,
                              void* d_out, int out_size, void* d_ws, size_t ws_size,
                              hipStream_t stream) {
    const float* x        = (const float*)d_in[0];
    const float* actions  = (const float*)d_in[1];
    const int*   senders  = (const int*)d_in[2];
    const int*   receivers= (const int*)d_in[3];
    const float* Wm1 = (const float*)d_in[5],  *bm1 = (const float*)d_in[6];
    const float* Wm2 = (const float*)d_in[7],  *bm2 = (const float*)d_in[8];
    const float* Wm3 = (const float*)d_in[9],  *bm3 = (const float*)d_in[10];
    const float* Wa1 = (const float*)d_in[11], *ba1 = (const float*)d_in[12];
    const float* Wa2 = (const float*)d_in[13], *ba2 = (const float*)d_in[14];
    const float* Wa3 = (const float*)d_in[15], *ba3 = (const float*)d_in[16];
    const float* Wu1 = (const float*)d_in[17], *bu1 = (const float*)d_in[18];
    const float* Wu2 = (const float*)d_in[19], *bu2 = (const float*)d_in[20];
    const float* Wu3 = (const float*)d_in[21], *bu3 = (const float*)d_in[22];
    const float* Wact= (const float*)d_in[23], *bact= (const float*)d_in[24];
    const float* Wh1 = (const float*)d_in[25], *bh1 = (const float*)d_in[26];
    const float* Wh2 = (const float*)d_in[27], *bh2 = (const float*)d_in[28];
    const float* Wq  = (const float*)d_in[29], *bq  = (const float*)d_in[30];

    const int E = in_sizes[2];
    const int n_agents = out_size;

    // ws: [0,1024) cnts(FB ints) | [1024,+512K) aggr | pack (1.84M) | edges
    char* ws = (char*)d_ws;
    int*   cnts = (int*)ws;
    float* aggr = (float*)(ws + 1024);
    const size_t packOff = 1024 + (size_t)n_agents * 128 * sizeof(float);
    uint4* pack = (uint4*)(ws + packOff);
    const size_t packBytes = (size_t)2 * PK_TOTAL * 16;
    const size_t edgeOff = packOff + packBytes;
    int2* edges = (int2*)(ws + edgeOff);

    const int FB = (E + FILT_CHUNK - 1) / FILT_CHUNK;   // 196
    const int PB = (PK_TOTAL + 255) / 256;              // 224

    PackPtrs P;
    P.W[0] = Wm1; P.W[1] = Wm2; P.W[2] = Wm3;
    P.W[3] = Wa1; P.W[4] = Wa2; P.W[5] = Wa3;
    P.W[6] = Wu1; P.W[7] = Wu2; P.W[8] = Wu3;
    P.W[9] = Wh1; P.W[10] = Wh2;
    pack_and_filter<<<FB + PB, 256, 0, stream>>>(P, pack, senders, receivers,
                                                 E, n_agents, cnts, edges,
                                                 aggr, n_agents * 128, FB);

    edge_mlp<<<512, 256, 0, stream>>>(x, edges, cnts, aggr, pack,
                                      bm1, bm2, bm3, FB);

    node_update<<<(n_agents + 15) / 16, 256, 0, stream>>>(
        x, actions, aggr, n_agents, pack,
        ba1, ba2, ba3, bu1, bu2, bu3, Wact, bact, bh1, bh2, Wq, bq,
        (float*)d_out);
}

// Round 10
// 194.355 us; speedup vs baseline: 2.6026x; 1.2592x over previous
//
#include <hip/hip_runtime.h>
#include <hip/hip_bf16.h>

// ---------------------------------------------------------------------------
// CriticWithGNN. Only edges with receiver < n_agents (~2%) matter (output is
// q[:n_agents]). Dense layers on MFMA with split-precision bf16:
// A*W ~= Alo*Whi + Ahi*Wlo + Ahi*Whi  (rel err ~2^-17, fp32-grade).
// R10: remove R8's weight register double-buffer from edge_mlp — it blew the
// 128-VGPR budget and spilled (WRITE 8->55MB, the real R9 wall). Edge layer
// back to the R5/R7-proven single-buffer body. Node keeps dbuf (512-VGPR
// budget at 1 block/CU). Mapping/dispatch structure unchanged from R9.
// ---------------------------------------------------------------------------

#define STRIDE 260      // fp32 LDS row stride in words
#define FILT_CHUNK 4096 // edges scanned per filter block
#define CSTRIDE 1024    // compacted-edge slots per chunk (~84 expected)
#define TPC (CSTRIDE / 32)

typedef __attribute__((ext_vector_type(8))) short short8;
typedef __attribute__((ext_vector_type(4))) float floatx4;
union Frag8 { short8 s; uint u[4]; };

// hi = truncate-to-bf16 (mask), lo = RNE-bf16(f - hi)  [R5-proven, no spill]
__device__ __forceinline__ void cvt_hi_lo(const float4 f0, const float4 f1,
                                          Frag8& hi, Frag8& lo) {
    uint U[8] = { __float_as_uint(f0.x), __float_as_uint(f0.y),
                  __float_as_uint(f0.z), __float_as_uint(f0.w),
                  __float_as_uint(f1.x), __float_as_uint(f1.y),
                  __float_as_uint(f1.z), __float_as_uint(f1.w) };
    float F[8] = { f0.x, f0.y, f0.z, f0.w, f1.x, f1.y, f1.z, f1.w };
#pragma unroll
    for (int p = 0; p < 4; ++p) {
        uint a = U[2*p], b = U[2*p+1];
        hi.u[p] = (a >> 16) | (b & 0xFFFF0000u);
        float l0 = F[2*p]   - __uint_as_float(a & 0xFFFF0000u);
        float l1 = F[2*p+1] - __uint_as_float(b & 0xFFFF0000u);
        __hip_bfloat162 pl = __float22bfloat162_rn(make_float2(l0, l1));
        union { __hip_bfloat162 h; uint v; } cvt; cvt.h = pl;
        lo.u[p] = cvt.v;
    }
}

// ---- bf16 RNE split (weight packing) ----
__device__ __forceinline__ uint f2bf(float f) {
    uint u = __float_as_uint(f);
    return (u + 0x7FFFu + ((u >> 16) & 1u)) >> 16;
}
__device__ __forceinline__ float bf2f(uint h) { return __uint_as_float(h << 16); }
__device__ __forceinline__ uint split2(float f0, float f1, uint& lo) {
    uint h0 = f2bf(f0), h1 = f2bf(f1);
    uint l0 = f2bf(f0 - bf2f(h0)), l1 = f2bf(f1 - bf2f(h1));
    lo = l0 | (l1 << 16);
    return h0 | (h1 << 16);
}

// ---- packed-weight table (Wm1,Wm2,Wm3,Wa1,Wa2,Wa3,Wu1,Wu2,Wu3,Wh1,Wh2) ----
constexpr int PK_NIN[11]  = {128,256,256, 128,128,128, 192,256,256, 256,256};
constexpr int PK_NOUT[11] = {256,256,128, 128,128,128, 256,256,128, 256,256};
constexpr int pk_entries(int m) { return (PK_NIN[m]/32)*(PK_NOUT[m]/16)*64; }
constexpr int pk_cum(int m) { int s = 0; for (int i = 0; i < m; ++i) s += pk_entries(i); return s; }
constexpr int PK_TOTAL = pk_cum(11);       // 57344
constexpr int pk_off_hi(int m) { return 2*pk_cum(m); }
constexpr int pk_off_lo(int m) { return 2*pk_cum(m) + pk_entries(m); }

struct PackPtrs { const float* W[11]; };

// Merged dispatch: blocks [0,FB) compact chunk b's edges (receiver<n_agents)
// into edges[b*CSTRIDE ..], cnts[b]=count. Blocks [FB,FB+PB) pack weights
// into B-frag hi/lo planes AND zero aggr.
__global__ void pack_and_filter(PackPtrs P, uint4* __restrict__ pack,
                                const int* __restrict__ senders,
                                const int* __restrict__ receivers,
                                int E, int n_agents,
                                int* __restrict__ cnts,
                                int2* __restrict__ edges,
                                float* __restrict__ aggr, int aggrN, int FB) {
    __shared__ int lcount;
    __shared__ int2 lbuf[FILT_CHUNK];
    const int t = (int)threadIdx.x;
    if ((int)blockIdx.x < FB) {
        if (t == 0) lcount = 0;
        __syncthreads();
        int start = blockIdx.x * FILT_CHUNK;
        int end = min(start + FILT_CHUNK, E);
        for (int b0 = start; b0 < end; b0 += 256) {
            int idx = b0 + t;
            int r = -1, s = 0;
            bool pred = false;
            if (idx < end) {
                r = receivers[idx];
                pred = (r < n_agents);
                if (pred) s = senders[idx];
            }
            unsigned long long m = __ballot(pred);
            int lane = t & 63;
            int below = __popcll(m & ((1ull << lane) - 1));
            int cnt = __popcll(m);
            int wbase = 0;
            if (lane == 0 && cnt) wbase = atomicAdd(&lcount, cnt);
            wbase = __shfl(wbase, 0, 64);
            if (pred) lbuf[wbase + below] = make_int2(s, r);
        }
        __syncthreads();
        int c = min(lcount, CSTRIDE);
        if (t == 0) cnts[blockIdx.x] = c;
        int2* dst = edges + (size_t)blockIdx.x * CSTRIDE;
        for (int i = t; i < c; i += 256) dst[i] = lbuf[i];
        return;
    }
    int g = ((int)blockIdx.x - FB) * 256 + t;
    for (int i = g; i < aggrN; i += 224 * 256) aggr[i] = 0.f;   // PB=224
    if (g >= PK_TOTAL) return;
    int m = 0;
#pragma unroll
    for (int i = 1; i < 11; ++i) if (g >= pk_cum(i)) m = i;
    int local = g - pk_cum(m);
    const float* W = P.W[m];
    int NOUT = PK_NOUT[m], NT = NOUT / 16;
    int lane = local & 63;
    int tmp  = local >> 6;
    int nt = tmp % NT, kb = tmp / NT;
    int n  = nt * 16 + (lane & 15);
    int k0 = kb * 32 + (lane >> 4) * 8;
    uint hi[4], lo[4];
#pragma unroll
    for (int p = 0; p < 4; ++p) {
        float f0 = W[(size_t)(k0 + 2*p)     * NOUT + n];
        float f1 = W[(size_t)(k0 + 2*p + 1) * NOUT + n];
        hi[p] = split2(f0, f1, lo[p]);
    }
    pack[pk_off_hi(m) + local] = make_uint4(hi[0], hi[1], hi[2], hi[3]);
    pack[pk_off_lo(m) + local] = make_uint4(lo[0], lo[1], lo[2], lo[3]);
}

// ---- MFMA dense layer, 32-row tile, SINGLE-buffered weights (R5-proven;
// the R8 register double-buffer spilled at the 128-VGPR 2-blocks/CU budget)
template<int NIN, int NOUT, bool RELU>
__device__ __forceinline__ void mfma_layer(const float* in_lds, float* out_lds,
                                           const uint4* __restrict__ Whi,
                                           const uint4* __restrict__ Wlo,
                                           const float* __restrict__ b) {
    constexpr int KB  = NIN / 32;
    constexpr int NT  = NOUT / 16;
    constexpr int NTW = NT / 4;
    const int t    = (int)threadIdx.x;
    const int wave = t >> 6;
    const int l15  = t & 15;
    const int quad = (t >> 4) & 3;

    floatx4 acc[2][NTW];
#pragma unroll
    for (int mt = 0; mt < 2; ++mt)
#pragma unroll
        for (int i = 0; i < NTW; ++i) acc[mt][i] = (floatx4){0.f, 0.f, 0.f, 0.f};

#pragma unroll 2
    for (int kb = 0; kb < KB; ++kb) {
        Frag8 ahi[2], alo[2];
#pragma unroll
        for (int mt = 0; mt < 2; ++mt) {
            const float* src = in_lds + (mt * 16 + l15) * STRIDE + kb * 32 + quad * 8;
            cvt_hi_lo(*(const float4*)src, *(const float4*)(src + 4), ahi[mt], alo[mt]);
        }
#pragma unroll
        for (int i = 0; i < NTW; ++i) {
            int widx = (kb * NT + wave * NTW + i) * 64 + (t & 63);
            Frag8 bhi, blo;
            *(uint4*)bhi.u = Whi[widx];
            *(uint4*)blo.u = Wlo[widx];
#pragma unroll
            for (int mt = 0; mt < 2; ++mt) {
                acc[mt][i] = __builtin_amdgcn_mfma_f32_16x16x32_bf16(alo[mt].s, bhi.s, acc[mt][i], 0, 0, 0);
                acc[mt][i] = __builtin_amdgcn_mfma_f32_16x16x32_bf16(ahi[mt].s, blo.s, acc[mt][i], 0, 0, 0);
                acc[mt][i] = __builtin_amdgcn_mfma_f32_16x16x32_bf16(ahi[mt].s, bhi.s, acc[mt][i], 0, 0, 0);
            }
        }
    }
#pragma unroll
    for (int i = 0; i < NTW; ++i) {
        int n = (wave * NTW + i) * 16 + l15;
        float bias = b[n];
#pragma unroll
        for (int mt = 0; mt < 2; ++mt)
#pragma unroll
            for (int r = 0; r < 4; ++r) {
                float v = acc[mt][i][r] + bias;
                if (RELU) v = fmaxf(v, 0.f);
                out_lds[(mt * 16 + quad * 4 + r) * STRIDE + n] = v;
            }
    }
}

// ---- node-side helpers: weight dbuf OK here (1 block/CU -> 512-VGPR cap) --
template<int NT, int NTW>
__device__ __forceinline__ void loadW(const uint4* __restrict__ Whi,
                                      const uint4* __restrict__ Wlo,
                                      int k, int lane, int wave,
                                      Frag8 (&bh)[NTW], Frag8 (&bl)[NTW]) {
#pragma unroll
    for (int i = 0; i < NTW; ++i) {
        int widx = (k * NT + wave * NTW + i) * 64 + lane;
        *(uint4*)bh[i].u = Whi[widx];
        *(uint4*)bl[i].u = Wlo[widx];
    }
}

template<int NTW>
__device__ __forceinline__ void compute1(const float* in_lds, int kb,
                                         int l15, int quad,
                                         Frag8 (&bh)[NTW], Frag8 (&bl)[NTW],
                                         floatx4 (&acc)[NTW]) {
    Frag8 ahi, alo;
    const float* src = in_lds + l15 * STRIDE + kb * 32 + quad * 8;
    cvt_hi_lo(*(const float4*)src, *(const float4*)(src + 4), ahi, alo);
#pragma unroll
    for (int i = 0; i < NTW; ++i) {
        acc[i] = __builtin_amdgcn_mfma_f32_16x16x32_bf16(alo.s, bh[i].s, acc[i], 0, 0, 0);
        acc[i] = __builtin_amdgcn_mfma_f32_16x16x32_bf16(ahi.s, bl[i].s, acc[i], 0, 0, 0);
        acc[i] = __builtin_amdgcn_mfma_f32_16x16x32_bf16(ahi.s, bh[i].s, acc[i], 0, 0, 0);
    }
}

// 16-row layer with output column offset + weight register double-buffer.
template<int NIN, int NOUT, bool RELU, int OOFF>
__device__ __forceinline__ void mfma_layer16(const float* in_lds, float* out_lds,
                                             const uint4* __restrict__ Whi,
                                             const uint4* __restrict__ Wlo,
                                             const float* __restrict__ b) {
    constexpr int KB = NIN / 32, NT = NOUT / 16, NTW = NT / 4;
    static_assert(KB % 2 == 0, "even KB");
    const int t = (int)threadIdx.x;
    const int wave = t >> 6, lane = t & 63, l15 = t & 15, quad = (t >> 4) & 3;

    floatx4 acc[NTW];
#pragma unroll
    for (int i = 0; i < NTW; ++i) acc[i] = (floatx4){0.f, 0.f, 0.f, 0.f};

    Frag8 WAh[NTW], WAl[NTW], WBh[NTW], WBl[NTW];
    loadW<NT, NTW>(Whi, Wlo, 0, lane, wave, WAh, WAl);
#pragma unroll
    for (int kb = 0; kb < KB; kb += 2) {
        loadW<NT, NTW>(Whi, Wlo, kb + 1, lane, wave, WBh, WBl);
        compute1<NTW>(in_lds, kb, l15, quad, WAh, WAl, acc);
        if (kb + 2 < KB) loadW<NT, NTW>(Whi, Wlo, kb + 2, lane, wave, WAh, WAl);
        compute1<NTW>(in_lds, kb + 1, l15, quad, WBh, WBl, acc);
    }
#pragma unroll
    for (int i = 0; i < NTW; ++i) {
        int n = (wave * NTW + i) * 16 + l15;
        float bias = b[n];
#pragma unroll
        for (int r = 0; r < 4; ++r) {
            float v = acc[i][r] + bias;
            if (RELU) v = fmaxf(v, 0.f);
            out_lds[(quad * 4 + r) * STRIDE + OOFF + n] = v;
        }
    }
}

// ---- edge message MLP over chunked compacted edges + atomic scatter ------
// ti-MAJOR vtile mapping (R9): chunk = vt % FB spreads real tiles evenly.
#define ETE 32
__global__ __launch_bounds__(256, 2)
void edge_mlp(const float* __restrict__ x, const int2* __restrict__ edges,
              const int* __restrict__ cnts, float* __restrict__ aggr,
              const uint4* __restrict__ pack,
              const float* __restrict__ bm1, const float* __restrict__ bm2,
              const float* __restrict__ bm3, int FB) {
    __shared__ float bufA[ETE * STRIDE];
    __shared__ float bufB[ETE * STRIDE];
    __shared__ int sL[ETE], rL[ETE];
    const int t = (int)threadIdx.x;
    const int vtiles = FB * TPC;
    for (int vt = (int)blockIdx.x; vt < vtiles; vt += (int)gridDim.x) {
        const int chunk = vt % FB, ti = vt / FB;
        const int cnt = cnts[chunk];
        if (ti * 32 >= cnt) continue;
        const int2* ce = edges + (size_t)chunk * CSTRIDE;
        const int base = ti * 32;
        if (t < ETE) {
            int eg = base + t;
            int2 ed = (eg < cnt) ? ce[eg] : make_int2(0, -1);
            sL[t] = ed.x; rL[t] = ed.y;
        }
        __syncthreads();
        for (int idx = t; idx < ETE * 32; idx += 256) {
            int e = idx >> 5;
            int f4 = (idx & 31) * 4;
            int node = (f4 < 64) ? sL[e] : rL[e];
            float4 v = make_float4(0.f, 0.f, 0.f, 0.f);
            if (rL[e] >= 0) v = *(const float4*)(x + (size_t)node * 64 + (f4 & 63));
            *(float4*)(bufA + e * STRIDE + f4) = v;
        }
        __syncthreads();
        mfma_layer<128, 256, true >(bufA, bufB, pack + pk_off_hi(0), pack + pk_off_lo(0), bm1);
        __syncthreads();
        mfma_layer<256, 256, true >(bufB, bufA, pack + pk_off_hi(1), pack + pk_off_lo(1), bm2);
        __syncthreads();
        mfma_layer<256, 128, false>(bufA, bufB, pack + pk_off_hi(2), pack + pk_off_lo(2), bm3);
        __syncthreads();
        for (int idx = t; idx < ETE * 128; idx += 256) {
            int e = idx >> 7, o = idx & 127;
            if (rL[e] >= 0) {
                atomicAdd(&aggr[(size_t)rL[e] * 128 + o], bufB[e * STRIDE + o]);
            }
        }
        __syncthreads();
    }
}

// ---- fused node pipeline, MFMA: 16 nodes/block, 64 blocks ----------------
__global__ __launch_bounds__(256, 1)
void node_update(const float* __restrict__ x, const float* __restrict__ actions,
                 const float* __restrict__ aggr, int n_agents,
                 const uint4* __restrict__ pack,
                 const float* __restrict__ ba1, const float* __restrict__ ba2,
                 const float* __restrict__ ba3,
                 const float* __restrict__ bu1, const float* __restrict__ bu2,
                 const float* __restrict__ bu3,
                 const float* __restrict__ Wact, const float* __restrict__ bact,
                 const float* __restrict__ bh1, const float* __restrict__ bh2,
                 const float* __restrict__ Wq,  const float* __restrict__ bq,
                 float* __restrict__ out) {
    __shared__ float bufA[16 * STRIDE];
    __shared__ float bufB[16 * STRIDE];
    __shared__ float qpart[16][17];
    const int t = (int)threadIdx.x;
    const int base = (int)blockIdx.x * 16;

    for (int idx = t; idx < 16 * 32; idx += 256) {
        int e = idx >> 5, f4 = (idx & 31) * 4;
        float4 v = make_float4(0.f, 0.f, 0.f, 0.f);
        if (base + e < n_agents) v = *(const float4*)(aggr + (size_t)(base + e) * 128 + f4);
        *(float4*)(bufA + e * STRIDE + f4) = v;
    }
    __syncthreads();
    mfma_layer16<128, 128, true,  0 >(bufA, bufB, pack + pk_off_hi(3), pack + pk_off_lo(3), ba1);
    __syncthreads();
    mfma_layer16<128, 128, true,  0 >(bufB, bufA, pack + pk_off_hi(4), pack + pk_off_lo(4), ba2);
    __syncthreads();
    mfma_layer16<128, 128, false, 64>(bufA, bufB, pack + pk_off_hi(5), pack + pk_off_lo(5), ba3);
    for (int idx = t; idx < 16 * 16; idx += 256) {
        int e = idx >> 4, f4 = (idx & 15) * 4;
        float4 v = make_float4(0.f, 0.f, 0.f, 0.f);
        if (base + e < n_agents) v = *(const float4*)(x + (size_t)(base + e) * 64 + f4);
        *(float4*)(bufB + e * STRIDE + f4) = v;
    }
    __syncthreads();
    mfma_layer16<192, 256, true,  0 >(bufB, bufA, pack + pk_off_hi(6), pack + pk_off_lo(6), bu1);
    __syncthreads();
    mfma_layer16<256, 256, true,  0 >(bufA, bufB, pack + pk_off_hi(7), pack + pk_off_lo(7), bu2);
    __syncthreads();
    mfma_layer16<256, 128, false, 0 >(bufB, bufA, pack + pk_off_hi(8), pack + pk_off_lo(8), bu3);
    {
        int e = t >> 4, c0 = (t & 15) * 8;
        float accp[8];
#pragma unroll
        for (int c = 0; c < 8; ++c) accp[c] = bact[c0 + c];
        if (base + e < n_agents) {
#pragma unroll
            for (int k = 0; k < 16; ++k) {
                float av = actions[(size_t)(base + e) * 16 + k];
#pragma unroll
                for (int c = 0; c < 8; ++c)
                    accp[c] += av * Wact[(size_t)k * 128 + c0 + c];
            }
        }
#pragma unroll
        for (int c = 0; c < 8; ++c)
            bufA[e * STRIDE + 128 + c0 + c] = fmaxf(accp[c], 0.f);
    }
    __syncthreads();
    mfma_layer16<256, 256, true, 0>(bufA, bufB, pack + pk_off_hi(9),  pack + pk_off_lo(9),  bh1);
    __syncthreads();
    mfma_layer16<256, 256, true, 0>(bufB, bufA, pack + pk_off_hi(10), pack + pk_off_lo(10), bh2);
    __syncthreads();
    {
        int e = t >> 4, g = t & 15;
        const float* z = bufA + e * STRIDE + g * 16;
        const float* w = Wq + g * 16;
        float p = 0.f;
#pragma unroll
        for (int j = 0; j < 16; j += 4) {
            float4 zv = *(const float4*)(z + j);
            float4 wv = *(const float4*)(w + j);
            p += zv.x * wv.x + zv.y * wv.y + zv.z * wv.z + zv.w * wv.w;
        }
        qpart[e][g] = p;
    }
    __syncthreads();
    if (t < 16 && base + t < n_agents) {
        float s = bq[0];
#pragma unroll
        for (int g = 0; g < 16; ++g) s += qpart[t][g];
        out[base + t] = s;
    }
}

extern "C" void kernel_launch(void* const* d_in, const int* in_sizes, int n_in,
                              void* d_out, int out_size, void* d_ws, size_t ws_size,
                              hipStream_t stream) {
    const float* x        = (const float*)d_in[0];
    const float* actions  = (const float*)d_in[1];
    const int*   senders  = (const int*)d_in[2];
    const int*   receivers= (const int*)d_in[3];
    const float* Wm1 = (const float*)d_in[5],  *bm1 = (const float*)d_in[6];
    const float* Wm2 = (const float*)d_in[7],  *bm2 = (const float*)d_in[8];
    const float* Wm3 = (const float*)d_in[9],  *bm3 = (const float*)d_in[10];
    const float* Wa1 = (const float*)d_in[11], *ba1 = (const float*)d_in[12];
    const float* Wa2 = (const float*)d_in[13], *ba2 = (const float*)d_in[14];
    const float* Wa3 = (const float*)d_in[15], *ba3 = (const float*)d_in[16];
    const float* Wu1 = (const float*)d_in[17], *bu1 = (const float*)d_in[18];
    const float* Wu2 = (const float*)d_in[19], *bu2 = (const float*)d_in[20];
    const float* Wu3 = (const float*)d_in[21], *bu3 = (const float*)d_in[22];
    const float* Wact= (const float*)d_in[23], *bact= (const float*)d_in[24];
    const float* Wh1 = (const float*)d_in[25], *bh1 = (const float*)d_in[26];
    const float* Wh2 = (const float*)d_in[27], *bh2 = (const float*)d_in[28];
    const float* Wq  = (const float*)d_in[29], *bq  = (const float*)d_in[30];

    const int E = in_sizes[2];
    const int n_agents = out_size;

    // ws: [0,1024) cnts(FB ints) | [1024,+512K) aggr | pack (1.84M) | edges
    char* ws = (char*)d_ws;
    int*   cnts = (int*)ws;
    float* aggr = (float*)(ws + 1024);
    const size_t packOff = 1024 + (size_t)n_agents * 128 * sizeof(float);
    uint4* pack = (uint4*)(ws + packOff);
    const size_t packBytes = (size_t)2 * PK_TOTAL * 16;
    const size_t edgeOff = packOff + packBytes;
    int2* edges = (int2*)(ws + edgeOff);

    const int FB = (E + FILT_CHUNK - 1) / FILT_CHUNK;   // 196
    const int PB = (PK_TOTAL + 255) / 256;              // 224

    PackPtrs P;
    P.W[0] = Wm1; P.W[1] = Wm2; P.W[2] = Wm3;
    P.W[3] = Wa1; P.W[4] = Wa2; P.W[5] = Wa3;
    P.W[6] = Wu1; P.W[7] = Wu2; P.W[8] = Wu3;
    P.W[9] = Wh1; P.W[10] = Wh2;
    pack_and_filter<<<FB + PB, 256, 0, stream>>>(P, pack, senders, receivers,
                                                 E, n_agents, cnts, edges,
                                                 aggr, n_agents * 128, FB);

    edge_mlp<<<512, 256, 0, stream>>>(x, edges, cnts, aggr, pack,
                                      bm1, bm2, bm3, FB);

    node_update<<<(n_agents + 15) / 16, 256, 0, stream>>>(
        x, actions, aggr, n_agents, pack,
        ba1, ba2, ba3, bu1, bu2, bu3, Wact, bact, bh1, bh2, Wq, bq,
        (float*)d_out);
}